// Round 10
// baseline (298.213 us; speedup 1.0000x reference)
//
#include <hip/hip_runtime.h>

using bf16x8 = __attribute__((ext_vector_type(8))) short;
using short8 = __attribute__((ext_vector_type(8))) short;
using s16x4  = __attribute__((ext_vector_type(4))) short;
using f32x4  = __attribute__((ext_vector_type(4))) float;
using u32x4  = __attribute__((ext_vector_type(4))) unsigned;
using ull    = unsigned long long;

#define T_SEQ 512
#define MFMA(A, B, C) __builtin_amdgcn_mfma_f32_16x16x32_bf16((A), (B), (C), 0, 0, 0)

// Raw barrier: lgkmcnt(0) makes this wave's ds_write visible, s_barrier has NO
// fence semantics -> outstanding global x prefetches are NOT drained (unlike
// __syncthreads, which emits s_waitcnt vmcnt(0) and serializes HBM latency
// into every step). sched_barrier(0) pins ordering around the pair (rule #18).
#define BARRIER()                                            \
    do {                                                     \
        __builtin_amdgcn_sched_barrier(0);                   \
        asm volatile("s_waitcnt lgkmcnt(0)" ::: "memory");   \
        __builtin_amdgcn_s_barrier();                        \
        __builtin_amdgcn_sched_barrier(0);                   \
    } while (0)

static constexpr float NL2E  = -1.44269504f;   // -log2(e)
static constexpr float N2L2E = -2.88539008f;   // -2*log2(e)

// Truncation split: hi = bf16-truncate(v), lo = bf16-truncate(v - hi) (residual exact).
__device__ __forceinline__ void split8_tr(f32x4 a, f32x4 b, bf16x8& hi, bf16x8& lo) {
    u32x4 ua = __builtin_bit_cast(u32x4, a);
    u32x4 ub = __builtin_bit_cast(u32x4, b);
    u32x4 m  = {0xffff0000u, 0xffff0000u, 0xffff0000u, 0xffff0000u};
    f32x4 ra = a - __builtin_bit_cast(f32x4, ua & m);
    f32x4 rb = b - __builtin_bit_cast(f32x4, ub & m);
    short8 sa  = __builtin_bit_cast(short8, a);
    short8 sb  = __builtin_bit_cast(short8, b);
    short8 sra = __builtin_bit_cast(short8, ra);
    short8 srb = __builtin_bit_cast(short8, rb);
    hi = __builtin_shufflevector(sa, sb, 1, 3, 5, 7, 9, 11, 13, 15);
    lo = __builtin_shufflevector(sra, srb, 1, 3, 5, 7, 9, 11, 13, 15);
}

__device__ __forceinline__ void split4_tr(f32x4 a, s16x4& hi, s16x4& lo) {
    u32x4 ua = __builtin_bit_cast(u32x4, a);
    u32x4 m  = {0xffff0000u, 0xffff0000u, 0xffff0000u, 0xffff0000u};
    f32x4 ra = a - __builtin_bit_cast(f32x4, ua & m);
    short8 sa  = __builtin_bit_cast(short8, a);
    short8 sra = __builtin_bit_cast(short8, ra);
    hi = __builtin_shufflevector(sa, sa, 1, 3, 5, 7);
    lo = __builtin_shufflevector(sra, sra, 1, 3, 5, 7);
}

// Gates for this wave's 4 hidden units. aR/aZ are state+input merged pre-acts;
// n-gate keeps input side (iN) and state side (sN) separate. Level-major 4-wide.
__device__ __forceinline__ void gate4(f32x4 aR, f32x4 aZ, f32x4 iN, f32x4 sN,
                                      float (&hf)[4]) {
    float er[4], ez[4];
    #pragma unroll
    for (int j = 0; j < 4; ++j) er[j] = __builtin_amdgcn_exp2f(aR[j] * NL2E);
    #pragma unroll
    for (int j = 0; j < 4; ++j) ez[j] = __builtin_amdgcn_exp2f(aZ[j] * NL2E);
    float gr[4], gz[4];
    #pragma unroll
    for (int j = 0; j < 4; ++j) gr[j] = __builtin_amdgcn_rcpf(1.f + er[j]);
    #pragma unroll
    for (int j = 0; j < 4; ++j) gz[j] = __builtin_amdgcn_rcpf(1.f + ez[j]);
    float en[4];
    #pragma unroll
    for (int j = 0; j < 4; ++j) {
        float u = fmaf(gr[j], sN[j], iN[j]);
        en[j] = __builtin_amdgcn_exp2f(fminf(u * N2L2E, 126.f));
    }
    float qn[4];
    #pragma unroll
    for (int j = 0; j < 4; ++j) qn[j] = __builtin_amdgcn_rcpf(1.f + en[j]);
    #pragma unroll
    for (int j = 0; j < 4; ++j) {
        float nn = fmaf(en[j] * qn[j], -2.f, 1.f);
        hf[j] = fmaf(gz[j], hf[j] - nn, nn);
    }
}

// Block = 256 threads = 4 waves = (layer L, row-half m). Wave (L,m) owns tiles
// {m, 2+m, 4+m} (r,z,n for hidden units 16m+4q+j) and publishes its 4 h/lane to
// LDS; half0's outputs are frag elements 0..3, half1's are 4..7 at the SAME
// lane, so a full state B-frag is one contiguous 16B ds_read per lane.
// Frag map: batch = b0+(lane&15), q = lane>>4; elems 0..3 = units 4q+j,
// 4..7 = 16+4q+j (same map A and B). D: col=lane&15, row=4q+reg (m89).
__global__ __launch_bounds__(256, 1)
void gru2_quad(const float* __restrict__ x,
               const float* __restrict__ W_ih0, const float* __restrict__ W_hh0,
               const float* __restrict__ b_ih0, const float* __restrict__ b_hh0,
               const float* __restrict__ W_ih1, const float* __restrict__ W_hh1,
               const float* __restrict__ b_ih1, const float* __restrict__ b_hh1,
               const float* __restrict__ W_proj, const float* __restrict__ b_proj,
               float* __restrict__ out)
{
    const int tid  = threadIdx.x;
    const int wid  = tid >> 6;
    const int L    = wid >> 1;        // 0: layer0, 1: layer1
    const int m    = wid & 1;         // row half
    const int lane = tid & 63;
    const int r16  = lane & 15;
    const int q    = lane >> 4;
    const int b0   = blockIdx.x * 16;

    // publications: [layer][parity][lane][half], hi and lo bf16 halves (8 KB)
    __shared__ ull pubH[2][2][64][2];
    __shared__ ull pubL[2][2][64][2];

    const float* Wx = L ? W_ih1 : W_ih0;
    const float* Wh = L ? W_hh1 : W_hh0;
    const float* bx = L ? b_ih1 : b_ih0;
    const float* bh = L ? b_hh1 : b_hh0;

    // weight fragments for tiles {m, 2+m, 4+m}; g: 0=r, 1=z, 2=n
    bf16x8 WxH[3], WxL[3], WhH[3], WhL[3];
    f32x4 bxf[3], bhf[3];
    #pragma unroll
    for (int g = 0; g < 3; ++g) {
        const int tile = 2 * g + m;
        const float* p1 = Wx + (16 * tile + r16) * 32 + 4 * q;
        split8_tr(*(const f32x4*)p1, *(const f32x4*)(p1 + 16), WxH[g], WxL[g]);
        const float* p2 = Wh + (16 * tile + r16) * 32 + 4 * q;
        split8_tr(*(const f32x4*)p2, *(const f32x4*)(p2 + 16), WhH[g], WhL[g]);
        bxf[g] = *(const f32x4*)(bx + 16 * tile + 4 * q);
        bhf[g] = *(const f32x4*)(bh + 16 * tile + 4 * q);
    }

    float hf[4] = {0.f, 0.f, 0.f, 0.f};
    bf16x8 inh = {}, inl = {};
    const float* xp = x + (size_t)(b0 + r16) * (T_SEQ * 32) + 4 * q;
    f32x4 xA = {}, xB = {};

    if (L == 0) {
        xA = *(const f32x4*)(xp);
        xB = *(const f32x4*)(xp + 16);
        // prologue: h0[0] from x[0], state = 0 (state accs = b_hh frags)
        split8_tr(xA, xB, inh, inl);
        xA = *(const f32x4*)(xp + 32);       // prefetch x[1]
        xB = *(const f32x4*)(xp + 48);
        f32x4 iR = MFMA(WxH[0], inh, bxf[0]);
        f32x4 iZ = MFMA(WxH[1], inh, bxf[1]);
        f32x4 iN = MFMA(WxH[2], inh, bxf[2]);
        iR = MFMA(WxH[0], inl, iR); iZ = MFMA(WxH[1], inl, iZ); iN = MFMA(WxH[2], inl, iN);
        iR = MFMA(WxL[0], inh, iR); iZ = MFMA(WxL[1], inh, iZ); iN = MFMA(WxL[2], inh, iN);
        gate4(iR + bhf[0], iZ + bhf[1], iN, bhf[2], hf);
        s16x4 hi4, lo4;
        split4_tr(f32x4{hf[0], hf[1], hf[2], hf[3]}, hi4, lo4);
        pubH[0][0][lane][m] = __builtin_bit_cast(ull, hi4);
        pubL[0][0][lane][m] = __builtin_bit_cast(ull, lo4);
    } else {
        // zero h1's initial state buffer (read at t=1 as pub1[1])
        if (m == 0) { pubH[1][1][lane][0] = 0; pubH[1][1][lane][1] = 0; }
        else        { pubL[1][1][lane][0] = 0; pubL[1][1][lane][1] = 0; }
    }

    // ---- main loop: wave (0,m) -> h0[t] half, wave (1,m) -> h1[t-1] half ----
    #pragma unroll 1
    for (int t = 1; t < T_SEQ; ++t) {
        BARRIER();                       // iter t-1 LDS pubs visible; vmcnt NOT drained
        const int pPrev = (t - 1) & 1;
        const int pCur  = t & 1;
        bf16x8 Sh, Sl;
        if (L == 0) {
            Sh = __builtin_bit_cast(bf16x8, *(const u32x4*)&pubH[0][pPrev][lane][0]);
            Sl = __builtin_bit_cast(bf16x8, *(const u32x4*)&pubL[0][pPrev][lane][0]);
            split8_tr(xA, xB, inh, inl); // x[t] (register) under the ds_read wait
            const float* nx = xp + (size_t)((t + 1 < T_SEQ) ? t + 1 : t) * 32;
            xA = *(const f32x4*)(nx);    // prefetch x[t+1]; drains at USE, not barrier
            xB = *(const f32x4*)(nx + 16);
        } else {
            inh = __builtin_bit_cast(bf16x8, *(const u32x4*)&pubH[0][pPrev][lane][0]);
            inl = __builtin_bit_cast(bf16x8, *(const u32x4*)&pubL[0][pPrev][lane][0]);
            Sh  = __builtin_bit_cast(bf16x8, *(const u32x4*)&pubH[1][pCur][lane][0]);
            Sl  = __builtin_bit_cast(bf16x8, *(const u32x4*)&pubL[1][pCur][lane][0]);
        }

        // 18 MFMAs: input-side chains first (L0: register inputs cover the
        // state ds_read latency), then state-side chains. 6 independent accs.
        f32x4 iR = MFMA(WxH[0], inh, bxf[0]);
        f32x4 iZ = MFMA(WxH[1], inh, bxf[1]);
        f32x4 iN = MFMA(WxH[2], inh, bxf[2]);
        iR = MFMA(WxH[0], inl, iR); iZ = MFMA(WxH[1], inl, iZ); iN = MFMA(WxH[2], inl, iN);
        iR = MFMA(WxL[0], inh, iR); iZ = MFMA(WxL[1], inh, iZ); iN = MFMA(WxL[2], inh, iN);
        f32x4 sR = MFMA(WhH[0], Sh, bhf[0]);
        f32x4 sZ = MFMA(WhH[1], Sh, bhf[1]);
        f32x4 sN = MFMA(WhH[2], Sh, bhf[2]);
        sR = MFMA(WhH[0], Sl, sR); sZ = MFMA(WhH[1], Sl, sZ); sN = MFMA(WhH[2], Sl, sN);
        sR = MFMA(WhL[0], Sh, sR); sZ = MFMA(WhL[1], Sh, sZ); sN = MFMA(WhL[2], Sh, sN);

        gate4(sR + iR, sZ + iZ, iN, sN, hf);

        s16x4 hi4, lo4;
        split4_tr(f32x4{hf[0], hf[1], hf[2], hf[3]}, hi4, lo4);
        const int pW = (L == 0) ? pCur : pPrev;   // L0 writes h0[t], L1 writes h1[t-1]
        pubH[L][pW][lane][m] = __builtin_bit_cast(ull, hi4);
        pubL[L][pW][lane][m] = __builtin_bit_cast(ull, lo4);
    }

    __syncthreads();                     // h0[511] (pub0[1]), h1[510] (pub1[0]) visible
    if (L == 1) {
        // final step: h1[511] from h0[511] and h1[510]
        bf16x8 i2h = __builtin_bit_cast(bf16x8, *(const u32x4*)&pubH[0][1][lane][0]);
        bf16x8 i2l = __builtin_bit_cast(bf16x8, *(const u32x4*)&pubL[0][1][lane][0]);
        bf16x8 Sh  = __builtin_bit_cast(bf16x8, *(const u32x4*)&pubH[1][0][lane][0]);
        bf16x8 Sl  = __builtin_bit_cast(bf16x8, *(const u32x4*)&pubL[1][0][lane][0]);
        f32x4 iR = MFMA(WxH[0], i2h, bxf[0]);
        f32x4 iZ = MFMA(WxH[1], i2h, bxf[1]);
        f32x4 iN = MFMA(WxH[2], i2h, bxf[2]);
        iR = MFMA(WxH[0], i2l, iR); iZ = MFMA(WxH[1], i2l, iZ); iN = MFMA(WxH[2], i2l, iN);
        iR = MFMA(WxL[0], i2h, iR); iZ = MFMA(WxL[1], i2h, iZ); iN = MFMA(WxL[2], i2h, iN);
        f32x4 sR = MFMA(WhH[0], Sh, bhf[0]);
        f32x4 sZ = MFMA(WhH[1], Sh, bhf[1]);
        f32x4 sN = MFMA(WhH[2], Sh, bhf[2]);
        sR = MFMA(WhH[0], Sl, sR); sZ = MFMA(WhH[1], Sl, sZ); sN = MFMA(WhH[2], Sl, sN);
        sR = MFMA(WhL[0], Sh, sR); sZ = MFMA(WhL[1], Sh, sZ); sN = MFMA(WhL[2], Sh, sN);
        gate4(sR + iR, sZ + iZ, iN, sN, hf);
        s16x4 hi4, lo4;
        split4_tr(f32x4{hf[0], hf[1], hf[2], hf[3]}, hi4, lo4);
        pubH[1][1][lane][m] = __builtin_bit_cast(ull, hi4);   // h1[511]
        pubL[1][1][lane][m] = __builtin_bit_cast(ull, lo4);
    }
    __syncthreads();

    if (wid == 2) {
        // projection: out[b][o] = b_proj[o] + sum_u W_proj[o][u] * h1[u]
        bf16x8 Hh = __builtin_bit_cast(bf16x8, *(const u32x4*)&pubH[1][1][lane][0]);
        bf16x8 Hl = __builtin_bit_cast(bf16x8, *(const u32x4*)&pubL[1][1][lane][0]);
        const float* pp = W_proj + r16 * 32 + 4 * q;
        bf16x8 Wph, Wpl;
        split8_tr(*(const f32x4*)pp, *(const f32x4*)(pp + 16), Wph, Wpl);
        f32x4 accp = *(const f32x4*)(b_proj + 4 * q);   // elem reg -> output 4q+reg
        accp = MFMA(Wph, Hh, accp);
        accp = MFMA(Wph, Hl, accp);
        accp = MFMA(Wpl, Hh, accp);
        #pragma unroll
        for (int rg = 0; rg < 4; ++rg)
            out[(b0 + r16) * 16 + 4 * q + rg] = accp[rg];
    }
}

extern "C" void kernel_launch(void* const* d_in, const int* in_sizes, int n_in,
                              void* d_out, int out_size, void* d_ws, size_t ws_size,
                              hipStream_t stream) {
    const float* x      = (const float*)d_in[0];
    const float* W_ih0  = (const float*)d_in[1];
    const float* W_hh0  = (const float*)d_in[2];
    const float* b_ih0  = (const float*)d_in[3];
    const float* b_hh0  = (const float*)d_in[4];
    const float* W_ih1  = (const float*)d_in[5];
    const float* W_hh1  = (const float*)d_in[6];
    const float* b_ih1  = (const float*)d_in[7];
    const float* b_hh1  = (const float*)d_in[8];
    const float* W_proj = (const float*)d_in[9];
    const float* b_proj = (const float*)d_in[10];
    float* out = (float*)d_out;

    const int nb   = in_sizes[0] / (T_SEQ * 32);   // 4096 batch elements
    const int grid = nb / 16;                      // 16 batches per 4-wave block

    hipLaunchKernelGGL(gru2_quad, dim3(grid), dim3(256), 0, stream,
                       x, W_ih0, W_hh0, b_ih0, b_hh0,
                       W_ih1, W_hh1, b_ih1, b_hh1, W_proj, b_proj, out);
}

// Round 11
// 295.612 us; speedup vs baseline: 1.0088x; 1.0088x over previous
//
#include <hip/hip_runtime.h>

using bf16x8 = __attribute__((ext_vector_type(8))) short;
using short8 = __attribute__((ext_vector_type(8))) short;
using s16x4  = __attribute__((ext_vector_type(4))) short;
using f32x4  = __attribute__((ext_vector_type(4))) float;
using u32x4  = __attribute__((ext_vector_type(4))) unsigned;
using ull    = unsigned long long;

#define T_SEQ 512
#define MFMA(A, B, C) __builtin_amdgcn_mfma_f32_16x16x32_bf16((A), (B), (C), 0, 0, 0)

// Raw barrier: lgkmcnt(0) makes this wave's ds_write visible; s_barrier has no
// vmcnt-drain. sched_barrier(0) pins ordering around the pair (rule #18).
#define BARRIER()                                            \
    do {                                                     \
        __builtin_amdgcn_sched_barrier(0);                   \
        asm volatile("s_waitcnt lgkmcnt(0)" ::: "memory");   \
        __builtin_amdgcn_s_barrier();                        \
        __builtin_amdgcn_sched_barrier(0);                   \
    } while (0)

static constexpr float NL2E  = -1.44269504f;   // -log2(e)
static constexpr float N2L2E = -2.88539008f;   // -2*log2(e)

// Truncation split: hi = bf16-truncate(v), lo = bf16-truncate(v - hi) (residual exact).
__device__ __forceinline__ void split8_tr(f32x4 a, f32x4 b, bf16x8& hi, bf16x8& lo) {
    u32x4 ua = __builtin_bit_cast(u32x4, a);
    u32x4 ub = __builtin_bit_cast(u32x4, b);
    u32x4 m  = {0xffff0000u, 0xffff0000u, 0xffff0000u, 0xffff0000u};
    f32x4 ra = a - __builtin_bit_cast(f32x4, ua & m);
    f32x4 rb = b - __builtin_bit_cast(f32x4, ub & m);
    short8 sa  = __builtin_bit_cast(short8, a);
    short8 sb  = __builtin_bit_cast(short8, b);
    short8 sra = __builtin_bit_cast(short8, ra);
    short8 srb = __builtin_bit_cast(short8, rb);
    hi = __builtin_shufflevector(sa, sb, 1, 3, 5, 7, 9, 11, 13, 15);
    lo = __builtin_shufflevector(sra, srb, 1, 3, 5, 7, 9, 11, 13, 15);
}

__device__ __forceinline__ void split4_tr(f32x4 a, s16x4& hi, s16x4& lo) {
    u32x4 ua = __builtin_bit_cast(u32x4, a);
    u32x4 m  = {0xffff0000u, 0xffff0000u, 0xffff0000u, 0xffff0000u};
    f32x4 ra = a - __builtin_bit_cast(f32x4, ua & m);
    short8 sa  = __builtin_bit_cast(short8, a);
    short8 sra = __builtin_bit_cast(short8, ra);
    hi = __builtin_shufflevector(sa, sa, 1, 3, 5, 7);
    lo = __builtin_shufflevector(sra, sra, 1, 3, 5, 7);
}

// Assemble a B-frag from two 8B halves: lo8 -> elements 0..3, hi8 -> 4..7.
__device__ __forceinline__ bf16x8 combine8(ull lo8, ull hi8) {
    u32x4 v = {(unsigned)lo8, (unsigned)(lo8 >> 32),
               (unsigned)hi8, (unsigned)(hi8 >> 32)};
    return __builtin_bit_cast(bf16x8, v);
}
// own half goes at position m (0 -> elements 0..3, 1 -> 4..7)
__device__ __forceinline__ bf16x8 combine8_sel(ull own, ull other, int m) {
    return combine8(m ? other : own, m ? own : other);
}

// 9-MFMA product block: 3 independent acc chains (hiW*hi, hiW*lo, loW*hi).
__device__ __forceinline__ void mfma9(const bf16x8 (&WH)[3], const bf16x8 (&WL)[3],
                                      bf16x8 inh, bf16x8 inl,
                                      f32x4 c0, f32x4 c1, f32x4 c2,
                                      f32x4& a0, f32x4& a1, f32x4& a2) {
    a0 = MFMA(WH[0], inh, c0); a1 = MFMA(WH[1], inh, c1); a2 = MFMA(WH[2], inh, c2);
    a0 = MFMA(WH[0], inl, a0); a1 = MFMA(WH[1], inl, a1); a2 = MFMA(WH[2], inl, a2);
    a0 = MFMA(WL[0], inh, a0); a1 = MFMA(WL[1], inh, a1); a2 = MFMA(WL[2], inh, a2);
}

// Gates for this wave's 4 hidden units; level-major 4-wide.
__device__ __forceinline__ void gate4(f32x4 aR, f32x4 aZ, f32x4 iN, f32x4 sN,
                                      float (&hf)[4]) {
    float er[4], ez[4];
    #pragma unroll
    for (int j = 0; j < 4; ++j) er[j] = __builtin_amdgcn_exp2f(aR[j] * NL2E);
    #pragma unroll
    for (int j = 0; j < 4; ++j) ez[j] = __builtin_amdgcn_exp2f(aZ[j] * NL2E);
    float gr[4], gz[4];
    #pragma unroll
    for (int j = 0; j < 4; ++j) gr[j] = __builtin_amdgcn_rcpf(1.f + er[j]);
    #pragma unroll
    for (int j = 0; j < 4; ++j) gz[j] = __builtin_amdgcn_rcpf(1.f + ez[j]);
    float en[4];
    #pragma unroll
    for (int j = 0; j < 4; ++j) {
        float u = fmaf(gr[j], sN[j], iN[j]);
        en[j] = __builtin_amdgcn_exp2f(fminf(u * N2L2E, 126.f));
    }
    float qn[4];
    #pragma unroll
    for (int j = 0; j < 4; ++j) qn[j] = __builtin_amdgcn_rcpf(1.f + en[j]);
    #pragma unroll
    for (int j = 0; j < 4; ++j) {
        float nn = fmaf(en[j] * qn[j], -2.f, 1.f);
        hf[j] = fmaf(gz[j], hf[j] - nn, nn);
    }
}

// Block = 256 threads = 4 waves = (layer L, row-half m). Own output half stays
// in registers (it IS elements [4m..4m+3] of next step's B-frag); only the
// other 8B half round-trips LDS. pub layout [half][layer][parity][lane] gives
// 8B lane stride (4-way bank aliasing vs 16B/8-way).
// Frag map: batch = b0+(lane&15), q = lane>>4; elems 0..3 = units 4q+j,
// 4..7 = 16+4q+j (same map A and B). D: col=lane&15, row=4q+reg (m89).
__global__ __launch_bounds__(256, 1)
void gru2_quad(const float* __restrict__ x,
               const float* __restrict__ W_ih0, const float* __restrict__ W_hh0,
               const float* __restrict__ b_ih0, const float* __restrict__ b_hh0,
               const float* __restrict__ W_ih1, const float* __restrict__ W_hh1,
               const float* __restrict__ b_ih1, const float* __restrict__ b_hh1,
               const float* __restrict__ W_proj, const float* __restrict__ b_proj,
               float* __restrict__ out)
{
    const int tid  = threadIdx.x;
    const int wid  = tid >> 6;
    const int L    = wid >> 1;        // 0: layer0, 1: layer1
    const int m    = wid & 1;         // row half
    const int lane = tid & 63;
    const int r16  = lane & 15;
    const int q    = lane >> 4;
    const int b0   = blockIdx.x * 16;

    // [half][layer][parity][lane] (8B each) -> 2KB + 2KB
    __shared__ ull pubH_[2][2][2][64];
    __shared__ ull pubL_[2][2][2][64];

    const float* Wx = L ? W_ih1 : W_ih0;
    const float* Wh = L ? W_hh1 : W_hh0;
    const float* bx = L ? b_ih1 : b_ih0;
    const float* bh = L ? b_hh1 : b_hh0;

    // weight fragments for tiles {m, 2+m, 4+m}; g: 0=r, 1=z, 2=n
    bf16x8 WxH[3], WxL[3], WhH[3], WhL[3];
    f32x4 bxf[3], bhf[3];
    #pragma unroll
    for (int g = 0; g < 3; ++g) {
        const int tile = 2 * g + m;
        const float* p1 = Wx + (16 * tile + r16) * 32 + 4 * q;
        split8_tr(*(const f32x4*)p1, *(const f32x4*)(p1 + 16), WxH[g], WxL[g]);
        const float* p2 = Wh + (16 * tile + r16) * 32 + 4 * q;
        split8_tr(*(const f32x4*)p2, *(const f32x4*)(p2 + 16), WhH[g], WhL[g]);
        bxf[g] = *(const f32x4*)(bx + 16 * tile + 4 * q);
        bhf[g] = *(const f32x4*)(bh + 16 * tile + 4 * q);
    }

    float hf[4] = {0.f, 0.f, 0.f, 0.f};
    ull ownH = 0, ownL = 0;                    // this wave's 4 h values, hi/lo bf16
    const float* xp = x + (size_t)(b0 + r16) * (T_SEQ * 32) + 4 * q;
    f32x4 xA = {}, xB = {};
    bf16x8 xh_cur = {}, xl_cur = {};

    if (L == 0) {
        f32x4 x0A = *(const f32x4*)(xp);
        f32x4 x0B = *(const f32x4*)(xp + 16);
        xA = *(const f32x4*)(xp + 32);         // x[1] in flight
        xB = *(const f32x4*)(xp + 48);
        split8_tr(x0A, x0B, xh_cur, xl_cur);   // x[0]
        // prologue: h0[0] from x[0], state = 0 (state accs = b_hh frags)
        f32x4 iR, iZ, iN;
        mfma9(WxH, WxL, xh_cur, xl_cur, bxf[0], bxf[1], bxf[2], iR, iZ, iN);
        gate4(iR + bhf[0], iZ + bhf[1], iN, bhf[2], hf);
        s16x4 hi4, lo4;
        split4_tr(f32x4{hf[0], hf[1], hf[2], hf[3]}, hi4, lo4);
        ownH = __builtin_bit_cast(ull, hi4);
        ownL = __builtin_bit_cast(ull, lo4);
        pubH_[m][0][0][lane] = ownH;           // publish h0[0] half
        pubL_[m][0][0][lane] = ownL;
        split8_tr(xA, xB, xh_cur, xl_cur);     // x[1] -> cur for iter 1
        xA = *(const f32x4*)(xp + 64);         // x[2] in flight
        xB = *(const f32x4*)(xp + 80);
    } else {
        // zero h1's initial state slot (read at t=1 as parity 1)
        pubH_[m][1][1][lane] = 0;
        pubL_[m][1][1][lane] = 0;
    }

    // ---- main loop: wave (0,m) -> h0[t] half, wave (1,m) -> h1[t-1] half ----
    #pragma unroll 1
    for (int t = 1; t < T_SEQ; ++t) {
        BARRIER();                       // prev-iter LDS pubs visible; no vmcnt drain
        const int pPrev = (t - 1) & 1;
        const int pCur  = t & 1;
        f32x4 iR, iZ, iN, sR, sZ, sN;
        if (L == 0) {
            ull oH = pubH_[1 - m][0][pPrev][lane];     // other h0 half (8B)
            ull oL = pubL_[1 - m][0][pPrev][lane];
            // input MFMAs start immediately: xh_cur pre-split last iteration
            mfma9(WxH, WxL, xh_cur, xl_cur, bxf[0], bxf[1], bxf[2], iR, iZ, iN);
            bf16x8 Sh = combine8_sel(ownH, oH, m);     // waits lgkmcnt here
            bf16x8 Sl = combine8_sel(ownL, oL, m);
            mfma9(WhH, WhL, Sh, Sl, bhf[0], bhf[1], bhf[2], sR, sZ, sN);
            split8_tr(xA, xB, xh_cur, xl_cur);         // x[t+1] (load 1 iter old)
            const int tn = (t + 2 < T_SEQ) ? t + 2 : T_SEQ - 1;
            xA = *(const f32x4*)(xp + (size_t)tn * 32);    // x[t+2] in flight
            xB = *(const f32x4*)(xp + (size_t)tn * 32 + 16);
        } else {
            ull i0H = pubH_[0][0][pPrev][lane];        // h0[t-1] halves (input)
            ull i1H = pubH_[1][0][pPrev][lane];
            ull i0L = pubL_[0][0][pPrev][lane];
            ull i1L = pubL_[1][0][pPrev][lane];
            ull oH  = pubH_[1 - m][1][pCur][lane];     // other h1[t-2] half
            ull oL  = pubL_[1 - m][1][pCur][lane];
            bf16x8 inh = combine8(i0H, i1H);
            bf16x8 inl = combine8(i0L, i1L);
            mfma9(WxH, WxL, inh, inl, bxf[0], bxf[1], bxf[2], iR, iZ, iN);
            bf16x8 Sh = combine8_sel(ownH, oH, m);
            bf16x8 Sl = combine8_sel(ownL, oL, m);
            mfma9(WhH, WhL, Sh, Sl, bhf[0], bhf[1], bhf[2], sR, sZ, sN);
        }

        gate4(sR + iR, sZ + iZ, iN, sN, hf);

        s16x4 hi4, lo4;
        split4_tr(f32x4{hf[0], hf[1], hf[2], hf[3]}, hi4, lo4);
        ownH = __builtin_bit_cast(ull, hi4);
        ownL = __builtin_bit_cast(ull, lo4);
        const int pW = (L == 0) ? pCur : pPrev;   // L0 writes h0[t], L1 h1[t-1]
        pubH_[m][L][pW][lane] = ownH;
        pubL_[m][L][pW][lane] = ownL;
    }

    __syncthreads();                     // h0[511] (p1), h1[510] (p0) visible
    if (L == 1) {
        // final step: h1[511] from h0[511] and h1[510]
        bf16x8 inh = combine8(pubH_[0][0][1][lane], pubH_[1][0][1][lane]);
        bf16x8 inl = combine8(pubL_[0][0][1][lane], pubL_[1][0][1][lane]);
        bf16x8 Sh  = combine8_sel(ownH, pubH_[1 - m][1][0][lane], m);
        bf16x8 Sl  = combine8_sel(ownL, pubL_[1 - m][1][0][lane], m);
        f32x4 iR, iZ, iN, sR, sZ, sN;
        mfma9(WxH, WxL, inh, inl, bxf[0], bxf[1], bxf[2], iR, iZ, iN);
        mfma9(WhH, WhL, Sh, Sl, bhf[0], bhf[1], bhf[2], sR, sZ, sN);
        gate4(sR + iR, sZ + iZ, iN, sN, hf);
        s16x4 hi4, lo4;
        split4_tr(f32x4{hf[0], hf[1], hf[2], hf[3]}, hi4, lo4);
        pubH_[m][1][1][lane] = __builtin_bit_cast(ull, hi4);   // h1[511]
        pubL_[m][1][1][lane] = __builtin_bit_cast(ull, lo4);
    }
    __syncthreads();

    if (wid == 2) {
        // projection: out[b][o] = b_proj[o] + sum_u W_proj[o][u] * h1[u]
        bf16x8 Hh = combine8(pubH_[0][1][1][lane], pubH_[1][1][1][lane]);
        bf16x8 Hl = combine8(pubL_[0][1][1][lane], pubL_[1][1][1][lane]);
        const float* pp = W_proj + r16 * 32 + 4 * q;
        bf16x8 Wph, Wpl;
        split8_tr(*(const f32x4*)pp, *(const f32x4*)(pp + 16), Wph, Wpl);
        f32x4 accp = *(const f32x4*)(b_proj + 4 * q);   // elem reg -> output 4q+reg
        accp = MFMA(Wph, Hh, accp);
        accp = MFMA(Wph, Hl, accp);
        accp = MFMA(Wpl, Hh, accp);
        #pragma unroll
        for (int rg = 0; rg < 4; ++rg)
            out[(b0 + r16) * 16 + 4 * q + rg] = accp[rg];
    }
}

extern "C" void kernel_launch(void* const* d_in, const int* in_sizes, int n_in,
                              void* d_out, int out_size, void* d_ws, size_t ws_size,
                              hipStream_t stream) {
    const float* x      = (const float*)d_in[0];
    const float* W_ih0  = (const float*)d_in[1];
    const float* W_hh0  = (const float*)d_in[2];
    const float* b_ih0  = (const float*)d_in[3];
    const float* b_hh0  = (const float*)d_in[4];
    const float* W_ih1  = (const float*)d_in[5];
    const float* W_hh1  = (const float*)d_in[6];
    const float* b_ih1  = (const float*)d_in[7];
    const float* b_hh1  = (const float*)d_in[8];
    const float* W_proj = (const float*)d_in[9];
    const float* b_proj = (const float*)d_in[10];
    float* out = (float*)d_out;

    const int nb   = in_sizes[0] / (T_SEQ * 32);   // 4096 batch elements
    const int grid = nb / 16;                      // 16 batches per 4-wave block

    hipLaunchKernelGGL(gru2_quad, dim3(grid), dim3(256), 0, stream,
                       x, W_ih0, W_hh0, b_ih0, b_hh0,
                       W_ih1, W_hh1, b_ih1, b_hh1, W_proj, b_proj, out);
}